// Round 9
// baseline (18922.823 us; speedup 1.0000x reference)
//
#include <hip/hip_runtime.h>
#include <math.h>

#define Bsz 512
#define HID 196
#define REC 488
#define NC  35
#define TT  120
#define G3  1464
#define NSLOT 123          // 4-deep pipeline: s in [0,123)

#define NB   61            // blocks per GEMM stage (8 out-cols each)
#define CELLB 32           // cell blocks (16 batch items each)
#define NGRID (3*NB + CELLB)   // 215 blocks <= 256 CUs -> all co-resident
#define WSL  (REC*24)      // per-block weight slice: [488 k][2 cw][12 cg]

// LDS: only cell blocks use it.
struct CellSmem { float xs[16][492]; float hs[16][36]; float rh[16][36]; };

__device__ __forceinline__ float sigmoidf_(float x) { return 1.0f / (1.0f + __expf(-x)); }

// ---- software grid barrier: release fence, RMW inc once, LOAD-poll, acquire ----
__device__ __forceinline__ void gbar(int* bar, int target) {
  __syncthreads();
  if (threadIdx.x == 0) {
    __builtin_amdgcn_fence(__ATOMIC_RELEASE, "agent");
    __hip_atomic_fetch_add(bar, 1, __ATOMIC_RELAXED, __HIP_MEMORY_SCOPE_AGENT);
    while (__hip_atomic_load(bar, __ATOMIC_RELAXED, __HIP_MEMORY_SCOPE_AGENT) < target)
      __builtin_amdgcn_s_sleep(2);
    __builtin_amdgcn_fence(__ATOMIC_ACQUIRE, "agent");
  }
  __syncthreads();
}

// ---- prologue: z = bn(X @ W.T + bias, g, beta) ----
__global__ void dense_bn_kernel(const float* __restrict__ X, const float* __restrict__ W,
                                const float* __restrict__ bias, const float* __restrict__ g,
                                const float* __restrict__ beta, float* __restrict__ Y) {
  __shared__ float xs[HID];
  int b = blockIdx.x;
  for (int k = threadIdx.x; k < HID; k += blockDim.x) xs[k] = X[(size_t)b*HID + k];
  __syncthreads();
  int j = threadIdx.x;
  if (j < HID) {
    const float4* wr = (const float4*)(W + (size_t)j*HID);
    float acc = 0.f;
    #pragma unroll 7
    for (int k4 = 0; k4 < HID/4; ++k4) {
      float4 w4 = wr[k4];
      acc += xs[4*k4+0]*w4.x + xs[4*k4+1]*w4.y + xs[4*k4+2]*w4.z + xs[4*k4+3]*w4.w;
    }
    float v = (acc + bias[j]) * 0.9995003746f;   // 1/sqrt(1+1e-3)
    Y[(size_t)b*HID + j] = g[j]*v + beta[j];
  }
}

// ---- prologue: xg0T[c][b] = (z @ Wih0.T + bih0)^T  (constant over T) ----
__global__ __launch_bounds__(256)
void xg0v2_kernel(const float* __restrict__ Z, const float* __restrict__ Wih,
                  const float* __restrict__ bih, float* __restrict__ XGT) {
  __shared__ float zs[HID*4];
  int b0 = blockIdx.x << 2;
  for (int idx = threadIdx.x; idx < HID*4; idx += 256) {
    int k = idx >> 2, i = idx & 3;
    zs[idx] = Z[(size_t)(b0+i)*HID + k];
  }
  __syncthreads();
  for (int c = threadIdx.x; c < G3; c += 256) {
    const float4* wr = (const float4*)(Wih + (size_t)c*HID);
    float a0=0.f,a1=0.f,a2=0.f,a3=0.f;
    for (int k4 = 0; k4 < HID/4; ++k4) {
      float4 w = wr[k4];
      const float* zp = zs + (k4<<4);
      a0=fmaf(w.x,zp[0],a0);  a1=fmaf(w.x,zp[1],a1);  a2=fmaf(w.x,zp[2],a2);  a3=fmaf(w.x,zp[3],a3);
      a0=fmaf(w.y,zp[4],a0);  a1=fmaf(w.y,zp[5],a1);  a2=fmaf(w.y,zp[6],a2);  a3=fmaf(w.y,zp[7],a3);
      a0=fmaf(w.z,zp[8],a0);  a1=fmaf(w.z,zp[9],a1);  a2=fmaf(w.z,zp[10],a2); a3=fmaf(w.z,zp[11],a3);
      a0=fmaf(w.w,zp[12],a0); a1=fmaf(w.w,zp[13],a1); a2=fmaf(w.w,zp[14],a2); a3=fmaf(w.w,zp[15],a3);
    }
    float bb = bih[c];
    XGT[(size_t)c*Bsz + b0+0] = a0 + bb;
    XGT[(size_t)c*Bsz + b0+1] = a1 + bb;
    XGT[(size_t)c*Bsz + b0+2] = a2 + bb;
    XGT[(size_t)c*Bsz + b0+3] = a3 + bb;
  }
}

// ---- prologue: weight slices, per-wave contiguous ----
// Wt[blk][k][cw*12 + g*4 + oc] = Wsrc[(g*488 + j*8 + cw*4 + oc)*488 + k]
__global__ __launch_bounds__(256)
void wtrans_kernel(const float* __restrict__ Whh0, const float* __restrict__ Wih1,
                   const float* __restrict__ Whh1, float* __restrict__ Wt) {
  int blk = blockIdx.x;                  // 3*61
  int stage = blk / NB, j = blk - stage*NB;
  const float* Wsrc = (stage==0) ? Whh0 : (stage==1) ? Wih1 : Whh1;
  float* dst = Wt + (size_t)blk*WSL;
  for (int idx = threadIdx.x; idx < WSL; idx += 256) {
    int k = idx / 24, t = idx - k*24;
    int cw = t / 12, u = t - cw*12;
    int g = u >> 2, oc = u & 3;
    dst[idx] = Wsrc[(size_t)(g*REC + j*8 + cw*4 + oc)*REC + k];
  }
}

// ---- acc[idx*2+r] += A rows(rbase,rbase+1) x 12 colgates, K=488 ----
// A [k][512] coalesced dwordx2; weights per-wave uniform 12/k, double-buffered
// in scalar regs (48 dwords per 4k chunk); unroll-by-2 ping-pong (no copies).
__device__ __forceinline__ void gemm2x12(const float* __restrict__ AT, int rbase,
                                         const float* __restrict__ wp,
                                         float (&acc)[24])
{
  float2 A0[4], A1[4];
  float  W0s[48], W1s[48];
  const float* abase = AT + rbase;
  #pragma unroll
  for (int kk = 0; kk < 4; ++kk) A0[kk] = *(const float2*)(abase + (size_t)kk*Bsz);
  #pragma unroll
  for (int kk = 0; kk < 4; ++kk)
    #pragma unroll
    for (int i = 0; i < 12; ++i) W0s[kk*12+i] = wp[kk*24 + i];

  for (int ck = 0; ck < 122; ck += 2) {
    int kb = ck*4;
    {   // prefetch odd chunk (always exists: last ck=120 -> kb+4=484<488)
      const float* an = abase + (size_t)(kb+4)*Bsz;
      const float* wn = wp + (size_t)(kb+4)*24;
      #pragma unroll
      for (int kk = 0; kk < 4; ++kk) A1[kk] = *(const float2*)(an + (size_t)kk*Bsz);
      #pragma unroll
      for (int kk = 0; kk < 4; ++kk)
        #pragma unroll
        for (int i = 0; i < 12; ++i) W1s[kk*12+i] = wn[kk*24 + i];
    }
    #pragma unroll
    for (int kk = 0; kk < 4; ++kk) {
      float x = A0[kk].x, y = A0[kk].y;
      #pragma unroll
      for (int i = 0; i < 12; ++i) {
        float wv = W0s[kk*12+i];
        acc[i*2+0] = fmaf(x, wv, acc[i*2+0]);
        acc[i*2+1] = fmaf(y, wv, acc[i*2+1]);
      }
    }
    if (ck + 2 < 122) {   // prefetch next even chunk
      const float* an = abase + (size_t)(kb+8)*Bsz;
      const float* wn = wp + (size_t)(kb+8)*24;
      #pragma unroll
      for (int kk = 0; kk < 4; ++kk) A0[kk] = *(const float2*)(an + (size_t)kk*Bsz);
      #pragma unroll
      for (int kk = 0; kk < 4; ++kk)
        #pragma unroll
        for (int i = 0; i < 12; ++i) W0s[kk*12+i] = wn[kk*24 + i];
    }
    #pragma unroll
    for (int kk = 0; kk < 4; ++kk) {
      float x = A1[kk].x, y = A1[kk].y;
      #pragma unroll
      for (int i = 0; i < 12; ++i) {
        float wv = W1s[kk*12+i];
        acc[i*2+0] = fmaf(x, wv, acc[i*2+0]);
        acc[i*2+1] = fmaf(y, wv, acc[i*2+1]);
      }
    }
  }
}

// ---- persistent kernel: 4-stage time pipeline, 215 blocks x 512 threads ----
// [0,61): GRU0 t=s | [61,122): GRU1 x-pass t=s-1 | [122,183): GRU1 h-pass t=s-2
// | [183,215): cell t=s-3.  Recurrent states TRANSPOSED [c][b]; hc normal.
// GEMM block: 512 rows x 8 out-cols; waves = 4 row-groups x 2 col-groups;
// thread = 2 rows x (4 oc x 3 gates).
__global__ __launch_bounds__(512)
void pers_kernel(const float* __restrict__ xg0T,
                 float* __restrict__ h0T, float* __restrict__ h1T,
                 float* __restrict__ xg1T, float* __restrict__ hc,
                 float* __restrict__ out,
                 const float* __restrict__ Wt,
                 const float* __restrict__ bhh0,
                 const float* __restrict__ bih1, const float* __restrict__ bhh1,
                 const float* __restrict__ cWih, const float* __restrict__ cWhh,
                 const float* __restrict__ cb, int* __restrict__ bar)
{
  __shared__ CellSmem S;
  const int blk = blockIdx.x;
  const int tid = threadIdx.x;
  const int stage = (blk < NB) ? 0 : (blk < 2*NB) ? 1 : (blk < 3*NB) ? 2 : 3;
  const int l = tid & 63, w = tid >> 6;
  const int w_u = __builtin_amdgcn_readfirstlane(w);   // force wave-uniform
  const int rw = w_u & 3, cw = w_u >> 2;
  const int rbase = rw*128 + 2*l;                      // 2 consecutive rows
  const float* wslice = Wt + (size_t)blk*WSL + cw*12;  // wave-uniform base
  const int jloc = blk - stage*NB;
  const int co0 = jloc*8 + cw*4;

  for (int s = 0; s < NSLOT; ++s) {
    if (stage == 0) {                    // ---------- GRU0, t = s ----------
      if (s < TT) {
        const float* hprevT = h0T + (size_t)((s+1)&1)*REC*Bsz;
        float*       hnewT  = h0T + (size_t)(s&1)*REC*Bsz;
        float acc[24] = {0};
        gemm2x12(hprevT, rbase, wslice, acc);
        #pragma unroll
        for (int oc = 0; oc < 4; ++oc) {
          int c = co0 + oc;
          float2 xr = *(const float2*)(xg0T + (size_t)c*Bsz + rbase);
          float2 xz = *(const float2*)(xg0T + (size_t)(REC+c)*Bsz + rbase);
          float2 xn = *(const float2*)(xg0T + (size_t)(2*REC+c)*Bsz + rbase);
          float2 hp = *(const float2*)(hprevT + (size_t)c*Bsz + rbase);
          float br = bhh0[c], bz = bhh0[REC+c], bn = bhh0[2*REC+c];
          float r0 = sigmoidf_(xr.x + acc[oc*2]       + br);
          float r1 = sigmoidf_(xr.y + acc[oc*2+1]     + br);
          float z0 = sigmoidf_(xz.x + acc[(4+oc)*2]   + bz);
          float z1 = sigmoidf_(xz.y + acc[(4+oc)*2+1] + bz);
          float n0 = tanhf(xn.x + r0*(acc[(8+oc)*2]   + bn));
          float n1 = tanhf(xn.y + r1*(acc[(8+oc)*2+1] + bn));
          float2 o;
          o.x = (1.f-z0)*n0 + z0*hp.x;
          o.y = (1.f-z1)*n1 + z1*hp.y;
          *(float2*)(hnewT + (size_t)c*Bsz + rbase) = o;
        }
      }
    } else if (stage == 1) {             // ---------- GRU1 x-pass, t = s-1 ----------
      if (s >= 1 && s <= TT) {
        int t1 = s - 1;
        const float* xT   = h0T  + (size_t)(t1&1)*REC*Bsz;
        float*       xgwT = xg1T + (size_t)(t1&1)*G3*Bsz;
        float acc[24] = {0};
        gemm2x12(xT, rbase, wslice, acc);
        #pragma unroll
        for (int oc = 0; oc < 4; ++oc) {
          int c = co0 + oc;
          float2 vr, vz, vn;
          vr.x = acc[oc*2];       vr.y = acc[oc*2+1];
          vz.x = acc[(4+oc)*2];   vz.y = acc[(4+oc)*2+1];
          vn.x = acc[(8+oc)*2];   vn.y = acc[(8+oc)*2+1];
          *(float2*)(xgwT + (size_t)c*Bsz + rbase)         = vr;
          *(float2*)(xgwT + (size_t)(REC+c)*Bsz + rbase)   = vz;
          *(float2*)(xgwT + (size_t)(2*REC+c)*Bsz + rbase) = vn;
        }
      }
    } else if (stage == 2) {             // ---------- GRU1 h-pass, t = s-2 ----------
      if (s >= 2 && s <= TT+1) {
        int t2 = s - 2;
        const float* hprevT = h1T  + (size_t)((t2+1)&1)*REC*Bsz;
        float*       hnewT  = h1T  + (size_t)(t2&1)*REC*Bsz;
        const float* xgrT   = xg1T + (size_t)(t2&1)*G3*Bsz;
        float acc[24] = {0};
        gemm2x12(hprevT, rbase, wslice, acc);
        #pragma unroll
        for (int oc = 0; oc < 4; ++oc) {
          int c = co0 + oc;
          float2 xr = *(const float2*)(xgrT + (size_t)c*Bsz + rbase);
          float2 xz = *(const float2*)(xgrT + (size_t)(REC+c)*Bsz + rbase);
          float2 xn = *(const float2*)(xgrT + (size_t)(2*REC+c)*Bsz + rbase);
          float2 hp = *(const float2*)(hprevT + (size_t)c*Bsz + rbase);
          float br = bih1[c] + bhh1[c];
          float bz = bih1[REC+c] + bhh1[REC+c];
          float bnx = bih1[2*REC+c], bnh = bhh1[2*REC+c];
          float r0 = sigmoidf_(xr.x + acc[oc*2]       + br);
          float r1 = sigmoidf_(xr.y + acc[oc*2+1]     + br);
          float z0 = sigmoidf_(xz.x + acc[(4+oc)*2]   + bz);
          float z1 = sigmoidf_(xz.y + acc[(4+oc)*2+1] + bz);
          float n0 = tanhf(xn.x + bnx + r0*(acc[(8+oc)*2]   + bnh));
          float n1 = tanhf(xn.y + bnx + r1*(acc[(8+oc)*2+1] + bnh));
          float2 o;
          o.x = (1.f-z0)*n0 + z0*hp.x;
          o.y = (1.f-z1)*n1 + z1*hp.y;
          *(float2*)(hnewT + (size_t)c*Bsz + rbase) = o;
        }
      }
    } else {                             // ---------- custom cell, t = s-3 ----------
      if (s >= 3) {
        int t3 = s - 3;
        int b0 = (blk - 3*NB) << 4;      // 16 items per block
        const float* xT = h1T + (size_t)(t3&1)*REC*Bsz;
        const float* hp = hc  + (size_t)((t3+1)&1)*Bsz*NC;
        float*       hn = hc  + (size_t)(t3&1)*Bsz*NC;
        for (int idx = tid; idx < 16*REC; idx += 512) {
          int k = idx >> 4, it = idx & 15;
          S.xs[it][k] = xT[(size_t)k*Bsz + b0 + it];
        }
        if (l < NC) {
          #pragma unroll
          for (int q = 0; q < 2; ++q) {
            int it = (w<<1) + q;
            S.hs[it][l] = hp[(size_t)(b0+it)*NC + l];
          }
        }
        __syncthreads();
        for (int q = 0; q < 2; ++q) {
          int it = (w<<1) + q;
          int b = b0 + it;
          float v = -1e30f, u = 0.f, hpc = 0.f;
          if (l < NC) {
            const float4* wr4 = (const float4*)(cWih + (size_t)l*REC);
            const float4* wz4 = (const float4*)(cWih + (size_t)(NC+l)*REC);
            const float4* wn4 = (const float4*)(cWih + (size_t)(2*NC+l)*REC);
            const float4* xs4 = (const float4*)(S.xs[it]);
            float xr=0.f, xz=0.f, xn=0.f;
            #pragma unroll 2
            for (int k4 = 0; k4 < REC/4; ++k4) {
              float4 xv = xs4[k4];
              float4 wa = wr4[k4], wb = wz4[k4], wc = wn4[k4];
              xr += wa.x*xv.x + wa.y*xv.y + wa.z*xv.z + wa.w*xv.w;
              xz += wb.x*xv.x + wb.y*xv.y + wb.z*xv.z + wb.w*xv.w;
              xn += wc.x*xv.x + wc.y*xv.y + wc.z*xv.z + wc.w*xv.w;
            }
            float hr=0.f, hz=0.f;
            for (int k = 0; k < NC; ++k) {
              float hv = S.hs[it][k];
              hr = fmaf(hv, cWhh[(size_t)l*NC + k], hr);
              hz = fmaf(hv, cWhh[(size_t)(NC+l)*NC + k], hz);
            }
            float r = sigmoidf_(xr + hr + cb[l]);
            u       = sigmoidf_(xz + hz + cb[NC+l]);
            hpc = S.hs[it][l];
            S.rh[it][l] = r * hpc;       // reference: (r*h) @ Whh_n.T
            v = xn;
          }
          __syncthreads();
          if (l < NC) {
            float hnn = 0.f;
            for (int k = 0; k < NC; ++k)
              hnn = fmaf(S.rh[it][k], cWhh[(size_t)(2*NC+l)*NC + k], hnn);
            v = v + hnn + cb[2*NC+l];
          }
          float m = v;
          #pragma unroll
          for (int o = 32; o; o >>= 1) m = fmaxf(m, __shfl_xor(m, o));
          float e = (l < NC) ? __expf(v - m) : 0.f;
          float ss = e;
          #pragma unroll
          for (int o = 32; o; o >>= 1) ss += __shfl_xor(ss, o);
          if (l < NC) {
            float h2 = (1.f - u)*(e/ss) + u*hpc;
            hn[(size_t)b*NC + l] = h2;
            out[((size_t)b*TT + t3)*NC + l] = h2;
          }
          __syncthreads();
        }
      }
    }
    gbar(bar, NGRID*(s+1));
  }
}

extern "C" void kernel_launch(void* const* d_in, const int* in_sizes, int n_in,
                              void* d_out, int out_size, void* d_ws, size_t ws_size,
                              hipStream_t stream) {
  const float* z_in  = (const float*)d_in[0];
  const float* W0    = (const float*)d_in[1];
  const float* b0    = (const float*)d_in[2];
  const float* g0    = (const float*)d_in[3];
  const float* beta0 = (const float*)d_in[4];
  const float* W1    = (const float*)d_in[5];
  const float* b1    = (const float*)d_in[6];
  const float* g1    = (const float*)d_in[7];
  const float* beta1 = (const float*)d_in[8];
  const float* Wih0  = (const float*)d_in[9];
  const float* Whh0  = (const float*)d_in[10];
  const float* bih0  = (const float*)d_in[11];
  const float* bhh0  = (const float*)d_in[12];
  const float* Wih1  = (const float*)d_in[13];
  const float* Whh1  = (const float*)d_in[14];
  const float* bih1  = (const float*)d_in[15];
  const float* bhh1  = (const float*)d_in[16];
  const float* cWih  = (const float*)d_in[17];
  const float* cWhh  = (const float*)d_in[18];
  const float* cbih  = (const float*)d_in[19];
  float* out = (float*)d_out;

  float* ws   = (float*)d_ws;
  int*   bar  = (int*)ws;                            // 256 slots (zeroed)
  float* h0T  = ws   + 256;                          // 2*REC*Bsz (zeroed)
  float* h1T  = h0T  + 2*(size_t)REC*Bsz;            // 2*REC*Bsz (zeroed)
  float* hcb  = h1T  + 2*(size_t)REC*Bsz;            // 2*Bsz*NC  (zeroed)
  float* xg1T = hcb  + 2*(size_t)Bsz*NC;             // 2*G3*Bsz
  float* xg0T = xg1T + 2*(size_t)G3*Bsz;             // G3*Bsz
  float* z1   = xg0T + (size_t)G3*Bsz;               // Bsz*HID
  float* z2   = z1   + (size_t)Bsz*HID;              // Bsz*HID
  float* Wt   = z2   + (size_t)Bsz*HID;              // 3*NB*WSL = 8.6 MB

  size_t zero_floats = 256 + 4*(size_t)REC*Bsz + 2*(size_t)Bsz*NC;
  hipMemsetAsync(ws, 0, zero_floats*sizeof(float), stream);

  dense_bn_kernel<<<Bsz, 256, 0, stream>>>(z_in, W0, b0, g0, beta0, z1);
  dense_bn_kernel<<<Bsz, 256, 0, stream>>>(z1,   W1, b1, g1, beta1, z2);
  xg0v2_kernel   <<<128, 256, 0, stream>>>(z2, Wih0, bih0, xg0T);
  wtrans_kernel  <<<3*NB, 256, 0, stream>>>(Whh0, Wih1, Whh1, Wt);

  pers_kernel<<<NGRID, 512, 0, stream>>>(xg0T, h0T, h1T, xg1T, hcb, out,
                                         Wt, bhh0, bih1, bhh1, cWih, cWhh, cbih, bar);
}